// Round 3
// baseline (43.382 us; speedup 1.0000x reference)
//
#include <hip/hip_runtime.h>

// Segment-mean over SORTED batch_ids, two-kernel row-split plan.
//
// Kernel 1: grid = G*SPLIT blocks. Block (g,q) sums the q-th contiguous ROW
//   chunk of graph g (full 1KB-contiguous row reads -> best DRAM pattern),
//   writes a 256-float partial to d_ws. q==0 block also writes the count.
//   Every ws slot we later read is written every call -> no memset, no
//   atomics, fully deterministic.
// Kernel 2: grid = G blocks; sums the 4 partials per graph, divides by count.
//
// Boundary search: windowed binary search around the expected position
// g*N/G (Binomial sigma <= ~224; window +/-4096 is ~18 sigma), validated
// with 2 guard loads, falling back to full range if invalid.

#define SPLIT 4

__global__ __launch_bounds__(256) void segmean_partial(
    const float* __restrict__ x,
    const int*   __restrict__ ids,
    float*       __restrict__ part,   // [G*SPLIT][D]
    int*         __restrict__ cnts,   // [G]
    int N, int D, int G)
{
    const int bid = (int)blockIdx.x;
    const int g   = bid >> 2;          // SPLIT == 4
    const int q   = bid & 3;

    // Windowed, interleaved lower_bound for v0 = g and v1 = g+1.
    const int W  = 4096;
    const int v0 = g, v1 = g + 1;
    const long long c0 = (long long)v0 * N / G;
    const long long c1 = (long long)v1 * N / G;
    int lo0 = (int)(c0 - W < 0 ? 0 : c0 - W);
    int hi0 = (int)(c0 + W > N ? N : c0 + W);
    int lo1 = (int)(c1 - W < 0 ? 0 : c1 - W);
    int hi1 = (int)(c1 + W > N ? N : c1 + W);
    // Validate that the true boundary lies inside each window; else full range.
    const bool ok0 = (lo0 == 0 || ids[lo0 - 1] < v0) && (hi0 == N || ids[hi0] >= v0);
    const bool ok1 = (lo1 == 0 || ids[lo1 - 1] < v1) && (hi1 == N || ids[hi1] >= v1);
    if (!ok0) { lo0 = 0; hi0 = N; }
    if (!ok1) { lo1 = 0; hi1 = N; }
    while ((lo0 < hi0) | (lo1 < hi1)) {
        if (lo0 < hi0) {
            const int m = (lo0 + hi0) >> 1;
            if (ids[m] < v0) lo0 = m + 1; else hi0 = m;
        }
        if (lo1 < hi1) {
            const int m = (lo1 + hi1) >> 1;
            if (ids[m] < v1) lo1 = m + 1; else hi1 = m;
        }
    }
    const int start = lo0, end = lo1;
    const int count = end - start;

    // This block's contiguous row chunk.
    const int chunk = (count + SPLIT - 1) >> 2;
    const int r0 = start + q * chunk;
    const int r1 = (r0 + chunk < end) ? (r0 + chunk) : end;

    const int t      = (int)threadIdx.x;
    const int rowoff = t >> 6;          // 4 rows per block-iteration
    const int col    = (t & 63) << 2;   // 64 lanes x float4 = full 1KB row

    float4 acc = make_float4(0.f, 0.f, 0.f, 0.f);
    #pragma unroll 4
    for (int r = r0 + rowoff; r < r1; r += 4) {
        const float4 v = *reinterpret_cast<const float4*>(x + (size_t)r * (size_t)D + col);
        acc.x += v.x; acc.y += v.y; acc.z += v.z; acc.w += v.w;
    }

    __shared__ float4 sd[256];
    sd[t] = acc;
    __syncthreads();

    if (t < 64) {
        const float4 a = sd[t];
        const float4 b = sd[t + 64];
        const float4 c = sd[t + 128];
        const float4 d = sd[t + 192];
        float4 s;
        s.x = (a.x + b.x) + (c.x + d.x);
        s.y = (a.y + b.y) + (c.y + d.y);
        s.z = (a.z + b.z) + (c.z + d.z);
        s.w = (a.w + b.w) + (c.w + d.w);
        *reinterpret_cast<float4*>(part + (size_t)bid * (size_t)D + col) = s;
    }
    if (q == 0 && t == 0) cnts[g] = count;
}

__global__ __launch_bounds__(256) void segmean_combine(
    const float* __restrict__ part,
    const int*   __restrict__ cnts,
    float*       __restrict__ out,
    int D)
{
    const int g = (int)blockIdx.x;
    const float inv = 1.0f / (float)cnts[g];
    const float* p = part + (size_t)g * SPLIT * (size_t)D;
    for (int d = (int)threadIdx.x; d < D; d += (int)blockDim.x) {
        const float s = (p[d] + p[d + D]) + (p[d + 2 * D] + p[d + 3 * D]);
        out[(size_t)g * (size_t)D + d] = s * inv;
    }
}

extern "C" void kernel_launch(void* const* d_in, const int* in_sizes, int n_in,
                              void* d_out, int out_size, void* d_ws, size_t ws_size,
                              hipStream_t stream) {
    const float* x   = (const float*)d_in[0];
    const int*   ids = (const int*)d_in[1];
    float*       out = (float*)d_out;

    const int N = in_sizes[1];            // 200000 rows
    const int D = in_sizes[0] / N;        // 256 features
    const int G = out_size / D;           // 512 graphs

    float* part = (float*)d_ws;                                   // G*SPLIT*D floats
    int*   cnts = (int*)((char*)d_ws + (size_t)G * SPLIT * D * sizeof(float));

    segmean_partial<<<dim3(G * SPLIT), dim3(256), 0, stream>>>(x, ids, part, cnts, N, D, G);
    segmean_combine<<<dim3(G), dim3(256), 0, stream>>>(part, cnts, out, D);
}

// Round 5
// 38.178 us; speedup vs baseline: 1.1363x; 1.1363x over previous
//
#include <hip/hip_runtime.h>

// Segment-mean over SORTED batch_ids. One block per graph, 1024 threads
// (16 waves) -> 2 blocks/CU = 32 waves/CU (full occupancy), vs 8 waves/CU in
// round 1. Full-row contiguous float4 reads (64 lanes x 16B = 1KB per wave
// instruction), nontemporal (read-once stream, skip cache allocation).
// Windowed binary search for segment boundaries (sorted ids are Binomial-
// concentrated around g*N/G; +/-4096 window = ~18 sigma, guarded + fallback).

typedef float f32x4 __attribute__((ext_vector_type(4)));

__global__ __launch_bounds__(1024) void segmean_kernel(
    const float* __restrict__ x,
    const int*   __restrict__ ids,
    float*       __restrict__ out,
    int N, int D, int G)
{
    const int g = (int)blockIdx.x;

    // Interleaved windowed lower_bound for v0 = g and v1 = g+1.
    const int W  = 4096;
    const int v0 = g, v1 = g + 1;
    const long long c0 = (long long)v0 * N / G;
    const long long c1 = (long long)v1 * N / G;
    int lo0 = (int)(c0 - W < 0 ? 0 : c0 - W);
    int hi0 = (int)(c0 + W > N ? N : c0 + W);
    int lo1 = (int)(c1 - W < 0 ? 0 : c1 - W);
    int hi1 = (int)(c1 + W > N ? N : c1 + W);
    const bool ok0 = (lo0 == 0 || ids[lo0 - 1] < v0) && (hi0 == N || ids[hi0] >= v0);
    const bool ok1 = (lo1 == 0 || ids[lo1 - 1] < v1) && (hi1 == N || ids[hi1] >= v1);
    if (!ok0) { lo0 = 0; hi0 = N; }
    if (!ok1) { lo1 = 0; hi1 = N; }
    while ((lo0 < hi0) | (lo1 < hi1)) {
        if (lo0 < hi0) {
            const int m = (lo0 + hi0) >> 1;
            if (ids[m] < v0) lo0 = m + 1; else hi0 = m;
        }
        if (lo1 < hi1) {
            const int m = (lo1 + hi1) >> 1;
            if (ids[m] < v1) lo1 = m + 1; else hi1 = m;
        }
    }
    const int start = lo0, end = lo1;
    const int count = end - start;

    const int t      = (int)threadIdx.x;
    const int rowoff = t >> 6;          // 16 rows per block-iteration
    const int col    = (t & 63) << 2;   // 64 lanes x float4 = full 1KB row

    f32x4 acc = (f32x4)(0.f);
    #pragma unroll 4
    for (int r = start + rowoff; r < end; r += 16) {
        const f32x4 v = __builtin_nontemporal_load(
            reinterpret_cast<const f32x4*>(x + (size_t)r * (size_t)D + col));
        acc += v;
    }

    // Tree-reduce the 16 rowoff groups ((t+512..) keeps the same column).
    __shared__ f32x4 sd[1024];   // 16 KiB
    sd[t] = acc;
    __syncthreads();
    if (t < 512) sd[t] += sd[t + 512];
    __syncthreads();
    if (t < 256) sd[t] += sd[t + 256];
    __syncthreads();
    if (t < 128) sd[t] += sd[t + 128];
    __syncthreads();
    if (t < 64) {
        const f32x4 s = sd[t] + sd[t + 64];
        const float inv = 1.0f / (float)count;  // empty segment: NaN, matches ref 0/0
        const f32x4 o = s * inv;
        *reinterpret_cast<f32x4*>(out + (size_t)g * (size_t)D + col) = o;
    }
}

extern "C" void kernel_launch(void* const* d_in, const int* in_sizes, int n_in,
                              void* d_out, int out_size, void* d_ws, size_t ws_size,
                              hipStream_t stream) {
    const float* x   = (const float*)d_in[0];
    const int*   ids = (const int*)d_in[1];
    float*       out = (float*)d_out;

    const int N = in_sizes[1];            // 200000 rows
    const int D = in_sizes[0] / N;        // 256 features
    const int G = out_size / D;           // 512 graphs

    segmean_kernel<<<dim3(G), dim3(1024), 0, stream>>>(x, ids, out, N, D, G);
}

// Round 6
// 37.247 us; speedup vs baseline: 1.1647x; 1.0250x over previous
//
#include <hip/hip_runtime.h>

// Segment-mean over SORTED batch_ids. One 1024-thread block per graph
// (2 blocks/CU = 32 waves/CU, full occupancy). Full-row contiguous float4
// nontemporal reads (64 lanes x 16B = 1KB per wave instruction; x is a
// read-once 205MB stream, skip cache allocation).
//
// Segment boundaries via WAVE-PARALLEL 64-ary search: each round, 64 lanes
// probe 64 positions, ballot+popcount narrows the range 64x. [0,200000]
// resolves in 3 gather rounds (~0.6us) vs 18 serial binary-search rounds
// (~2.2us of dead prologue latency). Wave 0 finds start, wave 1 finds end.

typedef float f32x4 __attribute__((ext_vector_type(4)));

__device__ __forceinline__ int lower_bound64(const int* __restrict__ ids,
                                             int N, int v, int lane)
{
    int lo = 0, hi = N;            // invariant: result in [lo, hi]
    while (hi > lo) {
        if (hi - lo <= 64) {       // exact round, step = 1
            const int p  = lo + lane;
            const bool lt = (p < hi) ? (ids[p] < v) : false;
            return lo + (int)__popcll(__ballot(lt));
        }
        const int step = (hi - lo + 63) >> 6;   // ceil(range/64)
        int p = lo + lane * step;
        if (p > hi - 1) p = hi - 1;
        const bool lt = ids[p] < v;
        const int cnt = (int)__popcll(__ballot(lt));   // prefix length (monotone)
        if (cnt > 0) {
            int q = lo + (cnt - 1) * step;
            if (q > hi - 1) q = hi - 1;
            lo = q + 1;                          // ids[q] < v -> result > q
        }
        if (cnt < 64) {
            int q = lo > hi ? hi : lo;           // keep lo<=hi safety
            q = (lo - 1) + 0;                    // (no-op; clarity)
            int r = ( (cnt > 0) ? (lo - 1) : lo ) ; (void)r;
            int qq = ( ( ( (cnt) * step ) + ( (cnt>0) ? (lo - 1 - (cnt-1)*step) : lo ) ) );
            // simpler recompute: first probe with ids >= v
            qq = ( (cnt) * step ) + ( (cnt>0) ? (lo - 1 - (cnt-1)*step) : lo );
            if (qq > hi - 1) qq = hi - 1;
            hi = qq;                             // ids[qq] >= v -> result <= qq
        }
    }
    return lo;
}

__global__ __launch_bounds__(1024) void segmean_kernel(
    const float* __restrict__ x,
    const int*   __restrict__ ids,
    float*       __restrict__ out,
    int N, int D, int G)
{
    const int g  = (int)blockIdx.x;
    const int t  = (int)threadIdx.x;
    const int wv = t >> 6;
    const int ln = t & 63;

    __shared__ int sb[2];
    if (wv == 0) {
        const int s = lower_bound64(ids, N, g, ln);
        if (ln == 0) sb[0] = s;
    } else if (wv == 1) {
        const int e = lower_bound64(ids, N, g + 1, ln);
        if (ln == 0) sb[1] = e;
    }
    __syncthreads();
    const int start = sb[0];
    const int end   = sb[1];
    const int count = end - start;

    const int rowoff = t >> 6;          // 16 rows per block-iteration
    const int col    = (t & 63) << 2;   // 64 lanes x float4 = full 1KB row

    f32x4 acc = (f32x4)(0.f);
    #pragma unroll 8
    for (int r = start + rowoff; r < end; r += 16) {
        const f32x4 v = __builtin_nontemporal_load(
            reinterpret_cast<const f32x4*>(x + (size_t)r * (size_t)D + col));
        acc += v;
    }

    // Tree-reduce the 16 rowoff groups (index+k*64 keeps the same column).
    __shared__ f32x4 sd[1024];   // 16 KiB
    sd[t] = acc;
    __syncthreads();
    if (t < 512) sd[t] += sd[t + 512];
    __syncthreads();
    if (t < 256) sd[t] += sd[t + 256];
    __syncthreads();
    if (t < 128) sd[t] += sd[t + 128];
    __syncthreads();
    if (t < 64) {
        const f32x4 s = sd[t] + sd[t + 64];
        const float inv = 1.0f / (float)count;  // empty segment: NaN, matches ref 0/0
        const f32x4 o = s * inv;
        *reinterpret_cast<f32x4*>(out + (size_t)g * (size_t)D + col) = o;
    }
}

extern "C" void kernel_launch(void* const* d_in, const int* in_sizes, int n_in,
                              void* d_out, int out_size, void* d_ws, size_t ws_size,
                              hipStream_t stream) {
    const float* x   = (const float*)d_in[0];
    const int*   ids = (const int*)d_in[1];
    float*       out = (float*)d_out;

    const int N = in_sizes[1];            // 200000 rows
    const int D = in_sizes[0] / N;        // 256 features
    const int G = out_size / D;           // 512 graphs

    segmean_kernel<<<dim3(G), dim3(1024), 0, stream>>>(x, ids, out, N, D, G);
}